// Round 6
// baseline (1635.070 us; speedup 1.0000x reference)
//
#include <hip/hip_runtime.h>

typedef unsigned short u16;
typedef unsigned int u32;
typedef __attribute__((ext_vector_type(8))) short short8;
typedef __attribute__((ext_vector_type(4))) float f32x4;
typedef __attribute__((ext_vector_type(4))) u32 u32x4;
typedef __attribute__((ext_vector_type(2))) u32 u32x2;

#define NN 100000
#define PAD 640

__device__ __forceinline__ float b2f(u16 u) {
    union { u32 i; float f; } v; v.i = ((u32)u) << 16; return v.f;
}
__device__ __forceinline__ u16 f2b(float f) {
    union { float f; u32 i; } v; v.f = f;
    u32 x = v.i;
    return (u16)((x + 0x7FFFu + ((x >> 16) & 1u)) >> 16);
}
__device__ __forceinline__ u32 pack2(float lo, float hi) {
    return (u32)f2b(lo) | ((u32)f2b(hi) << 16);
}
// read element i of a float tensor that is fp32 (f=1) or bf16 (f=0) on the wire
__device__ __forceinline__ float rdf(const void* p, size_t i, int f) {
    return f ? ((const float*)p)[i] : b2f(((const u16*)p)[i]);
}
// async global->LDS, 16B per lane; lptr must be wave-uniform
__device__ __forceinline__ void gload16(const u16* g, u16* l) {
    __builtin_amdgcn_global_load_lds(
        (const __attribute__((address_space(1))) void*)g,
        (__attribute__((address_space(3))) void*)l, 16, 0, 0);
}

// ---------------- dtype probes (wave-parallel) ----------------
__global__ void probe_k(const int* __restrict__ idx,
                        const void* avals, const void* feats, const void* W1,
                        const void* b1, const void* W2, const void* b2,
                        const void* Wfc, const void* bfc,
                        int* __restrict__ flags) {
    if (blockIdx.x != 0 || threadIdx.x >= 64) return;
    int lane = threadIdx.x;
    int v0 = idx[2 * lane + 1];
    int v1 = idx[2 * (lane + 64) + 1];
    int ok = (v0 == 0 && v1 == 0);
    int allz = __all(ok);
    if (lane == 0) flags[0] = allz ? 1 : 0;
    const void* ts[8] = {avals, feats, W1, b1, W2, b2, Wfc, bfc};
    const int ns[8] = {256, 256, 256, 128, 256, 128, 256, 32};
    for (int t = 0; t < 8; ++t) {
        const u16* p = (const u16*)ts[t];
        int n = ns[t], bad = 0;
        for (int i = lane; i < n; i += 64) {
            int e = (p[2 * i] >> 7) & 0xFF;
            if (e >= 133) bad++;
        }
        for (int off = 32; off; off >>= 1) bad += __shfl_xor(bad, off, 64);
        if (lane == 0) flags[1 + t] = (bad * 8 >= n) ? 1 : 0;
    }
}

__device__ __forceinline__ int load_row(const int* idx, int E, int f, int e) {
    return f ? idx[2 * e] : idx[e];
}
__device__ __forceinline__ int load_col(const int* idx, int E, int f, int e) {
    return f ? idx[2 * E + 2 * e] : idx[E + e];
}

// merged weight-transpose + bias conversion; blockIdx.y selects the job
// job4: bfc_adj[n] = bfc[n] + sum_{k<200} b2[0][k] * Wfc[k][n]  (copybias folded into FC)
__global__ void prep_k(const void* __restrict__ W1, const void* __restrict__ W2,
                       const void* __restrict__ Wfc,
                       const void* __restrict__ b1, const void* __restrict__ b2,
                       const void* __restrict__ bfc,
                       u16* __restrict__ w1t, u16* __restrict__ w2t,
                       u16* __restrict__ wfct, float* __restrict__ biasf,
                       const int* __restrict__ flags) {
    int i = blockIdx.x * 256 + threadIdx.x;
    int job = blockIdx.y;
    if (job == 0) {
        if (i >= 640 * 512) return;
        int n = i >> 9, k = i & 511;
        float v = 0.f;
        if (n < 600) {
            int ib = n / 200, c = n % 200;
            v = rdf(W1, (size_t)ib * 102400 + (size_t)k * 200 + c, flags[3]);
        }
        w1t[i] = f2b(v);
    } else if (job == 1) {
        if (i >= 640 * 640) return;
        int n = i / 640, k = i % 640;
        float v = 0.f;
        if (n < 600 && k < 600) {
            int ib = n / 200, c = n % 200;
            v = rdf(W2, (size_t)ib * 120000 + (size_t)k * 200 + c, flags[5]);
        }
        w2t[i] = f2b(v);
    } else if (job == 2) {
        if (i >= 64 * 640) return;
        int n = i / 640, k = i % 640;
        float v = 0.f;
        if (k < 600) v = rdf(Wfc, (size_t)k * 64 + n, flags[7]);
        wfct[i] = f2b(v);
    } else if (job == 3) {
        if (i < 600) biasf[i] = rdf(b1, i, flags[4]);
        else if (i < 1200) biasf[i] = rdf(b2, i - 600, flags[6]);
        else if (i < 1264) biasf[i] = rdf(bfc, i - 1200, flags[8]);
    } else {
        if (i >= 64) return;
        int fb2 = flags[6], fwf = flags[7];
        float s = rdf(bfc, i, flags[8]);
        for (int k = 0; k < 200; ++k)
            s += rdf(b2, k, fb2) * rdf(Wfc, (size_t)k * 64 + i, fwf);
        biasf[1280 + i] = s;
    }
}

// ---------------- CSR build (padded to 8 edges per row) ----------------
__device__ __forceinline__ int pad8(int c) { return (c + 7) & ~7; }

__global__ void count_k(const int* __restrict__ idx, int E, const int* __restrict__ flags,
                        int* __restrict__ counts) {
    int e = blockIdx.x * 256 + threadIdx.x;
    if (e >= E) return;
    int r = load_row(idx, E, flags[0], e);
    if ((u32)r >= NN) return;
    atomicAdd(&counts[r], 1);
}

__global__ void chunksum_k(const int* __restrict__ counts, int* __restrict__ chsum) {
    __shared__ int sm[256];
    int c = blockIdx.x, t = threadIdx.x;
    int base = c * 1024, s = 0;
    for (int i = t; i < 1024; i += 256) {
        int g = base + i;
        if (g < NN) s += pad8(counts[g]);
    }
    sm[t] = s; __syncthreads();
    for (int off = 128; off; off >>= 1) {
        if (t < off) sm[t] += sm[t + off];
        __syncthreads();
    }
    if (t == 0) chsum[c] = sm[0];
}

__global__ void chscan_k(const int* __restrict__ chsum, int nch, int* __restrict__ choff,
                         int* __restrict__ row_ptr, int E) {
    if (threadIdx.x == 0 && blockIdx.x == 0) {
        int run = 0;
        for (int c = 0; c < nch; ++c) { choff[c] = run; run += chsum[c]; }
        row_ptr[NN] = run;
    }
}

__global__ __launch_bounds__(1024) void scan_k(const int* __restrict__ counts,
                                               const int* __restrict__ choff,
                                               int* __restrict__ row_ptr,
                                               int* __restrict__ cursor) {
    __shared__ int sm[1024];
    int c = blockIdx.x, t = threadIdx.x;
    int g = c * 1024 + t;
    int v = (g < NN) ? pad8(counts[g]) : 0;
    sm[t] = v;
    __syncthreads();
    for (int off = 1; off < 1024; off <<= 1) {
        int add = (t >= off) ? sm[t - off] : 0;
        __syncthreads();
        sm[t] += add;
        __syncthreads();
    }
    if (g < NN) {
        int ex = choff[c] + sm[t] - v;
        row_ptr[g] = ex;
        cursor[g] = ex;
    }
}

// edges array: interleaved (col:int, val:f32) pairs
__global__ void scatter_k(const int* __restrict__ idx, const void* __restrict__ avals, int E,
                          const int* __restrict__ flags, int* __restrict__ cursor,
                          int* __restrict__ edges) {
    int e = blockIdx.x * 256 + threadIdx.x;
    if (e >= E) return;
    int f = flags[0];
    int r = load_row(idx, E, f, e);
    if ((u32)r >= NN) return;
    int c = load_col(idx, E, f, e);
    if ((u32)c >= NN) c = 0;
    int p = atomicAdd(&cursor[r], 1);
    edges[2 * p] = c;
    ((float*)edges)[2 * p + 1] = rdf(avals, e, flags[1]);
}

// fill padding slots with (col=0, val=0.0)
__global__ void padfill_k(const int* __restrict__ cursor, const int* __restrict__ row_ptr,
                          int* __restrict__ edges) {
    int r = blockIdx.x * 256 + threadIdx.x;
    if (r >= NN) return;
    int p = cursor[r], e = row_ptr[r + 1];
    for (; p < e; ++p) {
        edges[2 * p] = 0;
        ((float*)edges)[2 * p + 1] = 0.f;
    }
}

// ---------------- GEMM1: U = relu(feats @ W1all + b1), fused featconv+copypad ----------
// A = feats (fp32 or bf16 wire). Per-wave A-fragments loaded DIRECTLY global->reg in
// MFMA layout (no LDS round-trip): A-latency and B-latency overlap under one barrier
// drain instead of paying serially. LDS holds only the B tile (8 KB).
// Epilogue: C -> buf0 (all cols); side-copy to Cc=buf1 for col<200 and col>=600.
__global__ __launch_bounds__(256) void gemm1_k(
    const void* __restrict__ A, const u16* __restrict__ Bt,
    u16* __restrict__ C, u16* __restrict__ Cc,
    const float* __restrict__ bias, const int* __restrict__ flags,
    int M, int K, int lda, int ldc) {
    __shared__ u16 Bs[128 * 32];
    const int tid = threadIdx.x;
    const int wave = tid >> 6, lane = tid & 63;

    // bijective chunked XCD swizzle (m204)
    const int nwg = gridDim.x;
    const int q = nwg >> 3, r8 = nwg & 7;
    const int xcd = blockIdx.x & 7, lo = blockIdx.x >> 3;
    const int wg = (xcd < r8 ? xcd * (q + 1) : r8 * (q + 1) + (xcd - r8) * q) + lo;
    const int bmi = wg / 5, bni = wg - bmi * 5;
    const int bm = bmi * 128, bn = bni * 128;

    const int wrow = (wave >> 1) * 64, wcol = (wave & 1) * 64;
    const int l15 = lane & 15, l4 = lane >> 4;
    f32x4 acc[4][4] = {};

    const int ff = flags[2];
    // B staging (cooperative gload16, unchanged layout)
    const int c0 = wave * 2;
    const int rowB0 = c0 * 16 + (lane >> 2);
    const int rowB1 = rowB0 + 16;
    const int colE = (lane & 3) * 8;
    const u16* b0p = Bt + (size_t)(bn + rowB0) * K + colE;
    const u16* b1p = Bt + (size_t)(bn + rowB1) * K + colE;
    u16* lB0 = Bs + c0 * 512;
    u16* lB1 = Bs + c0 * 512 + 512;

    // per-wave A fragment base pointers (row = bm+wrow+mi*16+l15, col seg = l4*8)
    const float* af32[4];
    const u16* ah16[4];
#pragma unroll
    for (int mi = 0; mi < 4; ++mi) {
        int gr = bm + wrow + mi * 16 + l15;
        if (gr >= M) gr = M - 1;
        af32[mi] = (const float*)A + (size_t)gr * lda + l4 * 8;
        ah16[mi] = (const u16*)A + (size_t)gr * lda + l4 * 8;
    }

    for (int k0 = 0; k0 < K; k0 += 32) {
        __syncthreads();          // WAR on Bs (nothing outstanding here)
        gload16(b0p + k0, lB0);   // B: 2 async loads
        gload16(b1p + k0, lB1);
        short8 af[4];
        if (ff) {
            f32x4 x0[4], x1[4];
#pragma unroll
            for (int mi = 0; mi < 4; ++mi) {   // A: 8 reg loads, overlap with B
                x0[mi] = *(const f32x4*)(af32[mi] + k0);
                x1[mi] = *(const f32x4*)(af32[mi] + k0 + 4);
            }
#pragma unroll
            for (int mi = 0; mi < 4; ++mi)
#pragma unroll
                for (int t = 0; t < 4; ++t) {
                    af[mi][t] = (short)f2b(x0[mi][t]);
                    af[mi][t + 4] = (short)f2b(x1[mi][t]);
                }
        } else {
#pragma unroll
            for (int mi = 0; mi < 4; ++mi)
                af[mi] = *(const short8*)(ah16[mi] + k0);
        }
        __syncthreads();          // single drain: waits max(A-lat, B-lat), not sum
        short8 bf[4];
#pragma unroll
        for (int t = 0; t < 4; ++t)
            bf[t] = *(const short8*)&Bs[(wcol + t * 16 + l15) * 32 + l4 * 8];
#pragma unroll
        for (int mi = 0; mi < 4; ++mi)
#pragma unroll
            for (int ni = 0; ni < 4; ++ni)
                acc[mi][ni] = __builtin_amdgcn_mfma_f32_16x16x32_bf16(
                    af[mi], bf[ni], acc[mi][ni], 0, 0, 0);
    }

#pragma unroll
    for (int mi = 0; mi < 4; ++mi)
#pragma unroll
        for (int ni = 0; ni < 4; ++ni)
#pragma unroll
            for (int r4 = 0; r4 < 4; ++r4) {
                int row = bm + wrow + mi * 16 + l4 * 4 + r4;
                int col = bn + wcol + ni * 16 + l15;
                if (row < M) {
                    float v = acc[mi][ni][r4];
                    if (col < 600) v += bias[col];
                    v = fmaxf(v, 0.0f);
                    u16 b = f2b(v);
                    C[(size_t)row * ldc + col] = b;
                    if (col < 200 || col >= 600)
                        Cc[(size_t)row * ldc + col] = b;
                }
            }
}

// ---------------- 128x128 MFMA GEMM with global_load_lds (m97 structure) ----------------
// C[M x N=640] = A[M x K] * Bt[640 x K]^T ; 1D grid, n-tile fastest, XCD swizzle.
__global__ __launch_bounds__(256) void gemm128_k(
    const u16* __restrict__ A, const u16* __restrict__ Bt,
    u16* __restrict__ C, float* __restrict__ Cf,
    const float* __restrict__ bias, int bias_n, int relu,
    int M, int K, int lda, int ldc) {
    __shared__ u16 As[128 * 32];
    __shared__ u16 Bs[128 * 32];
    const int tid = threadIdx.x;
    const int wave = tid >> 6, lane = tid & 63;

    const int nwg = gridDim.x;
    const int q = nwg >> 3, r8 = nwg & 7;
    const int xcd = blockIdx.x & 7, lo = blockIdx.x >> 3;
    const int wg = (xcd < r8 ? xcd * (q + 1) : r8 * (q + 1) + (xcd - r8) * q) + lo;
    const int bmi = wg / 5, bni = wg - bmi * 5;
    const int bm = bmi * 128, bn = bni * 128;

    const int wrow = (wave >> 1) * 64, wcol = (wave & 1) * 64;
    const int l15 = lane & 15, l4 = lane >> 4;
    f32x4 acc[4][4] = {};

    const int c0 = wave * 2;
    const int rowA0 = c0 * 16 + (lane >> 2);
    const int rowA1 = rowA0 + 16;
    const int colE = (lane & 3) * 8;
    int gr0 = bm + rowA0; if (gr0 >= M) gr0 = M - 1;
    int gr1 = bm + rowA1; if (gr1 >= M) gr1 = M - 1;
    const u16* a0p = A + (size_t)gr0 * lda + colE;
    const u16* a1p = A + (size_t)gr1 * lda + colE;
    const u16* b0p = Bt + (size_t)(bn + rowA0) * K + colE;
    const u16* b1p = Bt + (size_t)(bn + rowA1) * K + colE;
    u16* lA0 = As + c0 * 512;
    u16* lA1 = As + c0 * 512 + 512;
    u16* lB0 = Bs + c0 * 512;
    u16* lB1 = Bs + c0 * 512 + 512;

    for (int k0 = 0; k0 < K; k0 += 32) {
        __syncthreads();
        gload16(a0p + k0, lA0);
        gload16(a1p + k0, lA1);
        gload16(b0p + k0, lB0);
        gload16(b1p + k0, lB1);
        __syncthreads();
        short8 af[4], bf[4];
#pragma unroll
        for (int t = 0; t < 4; ++t) {
            af[t] = *(const short8*)&As[(wrow + t * 16 + l15) * 32 + l4 * 8];
            bf[t] = *(const short8*)&Bs[(wcol + t * 16 + l15) * 32 + l4 * 8];
        }
#pragma unroll
        for (int mi = 0; mi < 4; ++mi)
#pragma unroll
            for (int ni = 0; ni < 4; ++ni)
                acc[mi][ni] = __builtin_amdgcn_mfma_f32_16x16x32_bf16(
                    af[mi], bf[ni], acc[mi][ni], 0, 0, 0);
    }

#pragma unroll
    for (int mi = 0; mi < 4; ++mi)
#pragma unroll
        for (int ni = 0; ni < 4; ++ni)
#pragma unroll
            for (int r4 = 0; r4 < 4; ++r4) {
                int row = bm + wrow + mi * 16 + l4 * 4 + r4;
                int col = bn + wcol + ni * 16 + l15;
                if (row < M) {
                    float v = acc[mi][ni][r4];
                    if (bias && col < bias_n) v += bias[col];
                    if (relu) v = fmaxf(v, 0.0f);
                    if (C) C[(size_t)row * ldc + col] = f2b(v);
                    if (Cf) Cf[(size_t)row * ldc + col] = v;
                }
            }
}

// ---------------- fused FC (128x64 tile, gload16 staging) + log_softmax ----------------
// node_emb[M x 64] = concat_k(A0[:,0:200], A1[:,200:640]) @ Wfct[64 x K]^T + bias
__global__ __launch_bounds__(256) void fc64_k(
    const u16* __restrict__ A0, const u16* __restrict__ A1,
    const u16* __restrict__ Bt,
    float* __restrict__ out_ne, float* __restrict__ out_pred,
    const float* __restrict__ bias, int M, int K, int lda) {
    __shared__ __align__(16) char ldsbuf[128 * 64 * 4];  // 32 KB
    u16* As = (u16*)ldsbuf;             // 128x32 bf16 = 8 KB
    u16* Bs = (u16*)(ldsbuf + 8192);    // 64x32 bf16 = 4 KB
    float* smC = (float*)ldsbuf;        // 128x64 f32 (epilogue reuse)

    const int tid = threadIdx.x;
    const int wave = tid >> 6, lane = tid & 63;
    const int bm = blockIdx.x * 128;
    const int wrow = (wave >> 1) * 64, wcol = (wave & 1) * 32;
    const int l15 = lane & 15, l4 = lane >> 4;
    f32x4 acc[4][2] = {};

    const int colE = (lane & 3) * 8;
    int gr0 = bm + wave * 32 + (lane >> 2); if (gr0 >= M) gr0 = M - 1;
    int gr1 = bm + wave * 32 + 16 + (lane >> 2); if (gr1 >= M) gr1 = M - 1;
    const u16* a0p0 = A0 + (size_t)gr0 * lda + colE;
    const u16* a0p1 = A1 + (size_t)gr0 * lda + colE;
    const u16* a1p0 = A0 + (size_t)gr1 * lda + colE;
    const u16* a1p1 = A1 + (size_t)gr1 * lda + colE;
    const u16* bp = Bt + (size_t)(wave * 16 + (lane >> 2)) * K + colE;
    u16* lA0 = As + wave * 1024;
    u16* lA1 = As + wave * 1024 + 512;
    u16* lB = Bs + wave * 512;

    for (int k0 = 0; k0 < K; k0 += 32) {
        const bool in0 = (k0 + colE) < 200;  // 8-col granularity; 200 % 8 == 0
        const u16* pa0 = in0 ? a0p0 : a0p1;
        const u16* pa1 = in0 ? a1p0 : a1p1;
        __syncthreads();
        gload16(pa0 + k0, lA0);
        gload16(pa1 + k0, lA1);
        gload16(bp + k0, lB);
        __syncthreads();
        short8 af[4], bf[2];
#pragma unroll
        for (int t = 0; t < 4; ++t)
            af[t] = *(const short8*)&As[(wrow + t * 16 + l15) * 32 + l4 * 8];
#pragma unroll
        for (int t = 0; t < 2; ++t)
            bf[t] = *(const short8*)&Bs[(wcol + t * 16 + l15) * 32 + l4 * 8];
#pragma unroll
        for (int mi = 0; mi < 4; ++mi)
#pragma unroll
            for (int ni = 0; ni < 2; ++ni)
                acc[mi][ni] = __builtin_amdgcn_mfma_f32_16x16x32_bf16(
                    af[mi], bf[ni], acc[mi][ni], 0, 0, 0);
    }

    __syncthreads();  // all waves out of the K-loop before LDS reuse
#pragma unroll
    for (int mi = 0; mi < 4; ++mi)
#pragma unroll
        for (int ni = 0; ni < 2; ++ni)
#pragma unroll
            for (int r4 = 0; r4 < 4; ++r4) {
                int rl = wrow + mi * 16 + l4 * 4 + r4;
                int col = wcol + ni * 16 + l15;
                int row = bm + rl;
                float v = acc[mi][ni][r4] + bias[col];
                smC[rl * 64 + col] = v;
                if (row < M) out_ne[(size_t)row * 64 + col] = v;
            }
    __syncthreads();

    // log_softmax: 2 threads per row, 32 cols each (rotated to avoid bank conflicts)
    const int rl = tid >> 1, half = tid & 1;
    const int row = bm + rl;
    float vv[32];
#pragma unroll
    for (int k = 0; k < 32; ++k) {
        int c = half * 32 + ((k + rl) & 31);
        vv[k] = smC[rl * 64 + c];
    }
    float m = vv[0];
#pragma unroll
    for (int k = 1; k < 32; ++k) m = fmaxf(m, vv[k]);
    m = fmaxf(m, __shfl_xor(m, 1, 64));
    float s = 0.f;
#pragma unroll
    for (int k = 0; k < 32; ++k) s += expf(vv[k] - m);
    s += __shfl_xor(s, 1, 64);
    float lg = m + logf(s);
    if (row < M) {
#pragma unroll
        for (int k = 0; k < 32; ++k) {
            int c = half * 32 + ((k + rl) & 31);
            out_pred[(size_t)row * 64 + c] = vv[k] - lg;
        }
    }
}

// ---------------- fused width-400 spmm: one wave per row, 8 gathers in flight --------
__global__ __launch_bounds__(256) void spmm400_k(
    const int* __restrict__ row_ptr, const int* __restrict__ edges,
    const u16* __restrict__ X, u16* __restrict__ Y1, u16* __restrict__ Yt,
    const float* __restrict__ bias1) {
    int r = blockIdx.x * 4 + (threadIdx.x >> 6);
    if (r >= NN) return;
    int lane = threadIdx.x & 63;
    int s = row_ptr[r], e = row_ptr[r + 1];
    if (s < 0) s = 0;
    if (e < s) e = s;
    float a[8] = {0.f, 0.f, 0.f, 0.f, 0.f, 0.f, 0.f, 0.f};
    const bool act = lane < 50;
    const u32* xl = (const u32*)X + lane * 4;
    for (int i = s; i < e; i += 8) {
        int cc[8]; float vv[8];
#pragma unroll
        for (int j = 0; j < 4; ++j) {
            u32x4 p = *(const u32x4*)(edges + 2 * (size_t)(i + 2 * j));
            union { u32 u; float f; } w0, w1;
            cc[2 * j] = (int)p[0];     w0.u = p[1];
            cc[2 * j + 1] = (int)p[2]; w1.u = p[3];
            vv[2 * j] = w0.f; vv[2 * j + 1] = w1.f;
        }
        if (act) {
            u32x4 g[8];
#pragma unroll
            for (int j = 0; j < 8; ++j) {
                u32 c = (u32)cc[j]; if (c >= NN) c = 0;
                g[j] = *(const u32x4*)(xl + (size_t)c * 320);
            }
#pragma unroll
            for (int j = 0; j < 8; ++j) {
                float v = vv[j];
#pragma unroll
                for (int q = 0; q < 4; ++q) {
                    union { u32 i; float f; } lo, hi;
                    lo.i = g[j][q] << 16; hi.i = g[j][q] & 0xffff0000u;
                    a[2 * q] = fmaf(v, lo.f, a[2 * q]);
                    a[2 * q + 1] = fmaf(v, hi.f, a[2 * q + 1]);
                }
            }
        }
    }
    if (bias1 && lane < 25) {
#pragma unroll
        for (int q = 0; q < 8; ++q) a[q] += bias1[lane * 8 + q];
    }
    u32x4 o;
    o[0] = pack2(a[0], a[1]); o[1] = pack2(a[2], a[3]);
    o[2] = pack2(a[4], a[5]); o[3] = pack2(a[6], a[7]);
    if (lane < 25) {
        *(u32x4*)((u32*)Y1 + (size_t)r * 320 + lane * 4) = o;
    } else if (lane < 50) {
        *(u32x4*)((u32*)Yt + (size_t)r * 100 + (lane - 25) * 4) = o;
    }
}

// ---------------- width-200 spmm: one wave per row, 8 gathers in flight --------------
__global__ __launch_bounds__(256) void spmm200_k(
    const int* __restrict__ row_ptr, const int* __restrict__ edges,
    const u16* __restrict__ X, int ldx,
    u16* __restrict__ Y, int ldy,
    const float* __restrict__ bias) {
    int r = blockIdx.x * 4 + (threadIdx.x >> 6);
    if (r >= NN) return;
    int lane = threadIdx.x & 63;
    int s = row_ptr[r], e = row_ptr[r + 1];
    if (s < 0) s = 0;
    if (e < s) e = s;
    float a[4] = {0.f, 0.f, 0.f, 0.f};
    const bool act = lane < 50;
    const int ldxw = ldx >> 1, ldyw = ldy >> 1;
    const u32* xl = (const u32*)X + lane * 2;
    for (int i = s; i < e; i += 8) {
        int cc[8]; float vv[8];
#pragma unroll
        for (int j = 0; j < 4; ++j) {
            u32x4 p = *(const u32x4*)(edges + 2 * (size_t)(i + 2 * j));
            union { u32 u; float f; } w0, w1;
            cc[2 * j] = (int)p[0];     w0.u = p[1];
            cc[2 * j + 1] = (int)p[2]; w1.u = p[3];
            vv[2 * j] = w0.f; vv[2 * j + 1] = w1.f;
        }
        if (act) {
            u32x2 g[8];
#pragma unroll
            for (int j = 0; j < 8; ++j) {
                u32 c = (u32)cc[j]; if (c >= NN) c = 0;
                g[j] = *(const u32x2*)(xl + (size_t)c * ldxw);
            }
#pragma unroll
            for (int j = 0; j < 8; ++j) {
                float v = vv[j];
#pragma unroll
                for (int q = 0; q < 2; ++q) {
                    union { u32 i; float f; } lo, hi;
                    lo.i = g[j][q] << 16; hi.i = g[j][q] & 0xffff0000u;
                    a[2 * q] = fmaf(v, lo.f, a[2 * q]);
                    a[2 * q + 1] = fmaf(v, hi.f, a[2 * q + 1]);
                }
            }
        }
    }
    if (bias && act) {
#pragma unroll
        for (int q = 0; q < 4; ++q) a[q] += bias[lane * 4 + q];
    }
    if (act) {
        u32x2 o;
        o[0] = pack2(a[0], a[1]); o[1] = pack2(a[2], a[3]);
        *(u32x2*)((u32*)Y + (size_t)r * ldyw + lane * 2) = o;
    }
}

extern "C" void kernel_launch(void* const* d_in, const int* in_sizes, int n_in,
                              void* d_out, int out_size, void* d_ws, size_t ws_size,
                              hipStream_t stream) {
    const int* adj_idx = (const int*)d_in[0];
    const void* adj_vals = d_in[1];
    const void* feats = d_in[2];
    const void* W1 = d_in[3];
    const void* b1 = d_in[4];
    const void* W2 = d_in[5];
    const void* b2 = d_in[6];
    const void* Wfc = d_in[7];
    const void* bfc = d_in[8];
    const int E = in_sizes[1];
    (void)n_in; (void)out_size; (void)ws_size;

    char* ws = (char*)d_ws;
    size_t off = 0;
    auto alloc = [&](size_t b) { size_t o = off; off += (b + 255) & ~(size_t)255; return o; };
    u16* buf0 = (u16*)(ws + alloc((size_t)NN * PAD * 2));   // U, then V
    u16* buf1 = (u16*)(ws + alloc((size_t)NN * PAD * 2));   // abstract1, stage-2 hops
    u16* hop = (u16*)(ws + alloc((size_t)NN * 200 * 2));
    u16* w1t = (u16*)(ws + alloc((size_t)640 * 512 * 2));
    u16* w2t = (u16*)(ws + alloc((size_t)640 * 640 * 2));
    u16* wfct = (u16*)(ws + alloc((size_t)64 * 640 * 2));
    float* biasf = (float*)(ws + alloc(1344 * 4));  // b1|b2|bfc|bfc_adj(1280+)
    int* counts = (int*)(ws + alloc((size_t)NN * 4));
    int* cursor = (int*)(ws + alloc((size_t)NN * 4));
    int* row_ptr = (int*)(ws + alloc((size_t)(NN + 1) * 4));
    int* chsum = (int*)(ws + alloc(4096));
    int* choff = (int*)(ws + alloc(4096));
    int* flags = (int*)(ws + alloc(256));
    // interleaved (col, val) pairs; padded to multiple of 8 per row
    int* edgesS = (int*)(ws + alloc(((size_t)E + 8 * (size_t)NN) * 8));

    float* out_ne = (float*)d_out;              // fp32 node_emb
    float* out_pred = out_ne + (size_t)NN * 64; // fp32 log-softmax

    // probes + weight prep
    probe_k<<<1, 64, 0, stream>>>(adj_idx, adj_vals, feats, W1, b1, W2, b2, Wfc, bfc, flags);
    dim3 gp(1600, 5);
    prep_k<<<gp, 256, 0, stream>>>(W1, W2, Wfc, b1, b2, bfc, w1t, w2t, wfct, biasf, flags);

    // CSR build (padded to 8 edges/row)
    hipMemsetAsync(counts, 0, NN * 4, stream);
    count_k<<<(E + 255) / 256, 256, 0, stream>>>(adj_idx, E, flags, counts);
    const int NCH = (NN + 1023) / 1024;  // 98
    chunksum_k<<<NCH, 256, 0, stream>>>(counts, chsum);
    chscan_k<<<1, 64, 0, stream>>>(chsum, NCH, choff, row_ptr, E);
    scan_k<<<NCH, 1024, 0, stream>>>(counts, choff, row_ptr, cursor);
    scatter_k<<<(E + 255) / 256, 256, 0, stream>>>(adj_idx, adj_vals, E, flags, cursor, edgesS);
    padfill_k<<<(NN + 255) / 256, 256, 0, stream>>>(cursor, row_ptr, edgesS);

    const int NWG = ((NN + 127) / 128) * 5;  // 782 M-tiles x 5 N-tiles = 3910
    // U = relu(feats @ W1all + b1) -> buf0; side-copy block0 + zero pad -> buf1
    gemm1_k<<<NWG, 256, 0, stream>>>(feats, w1t, buf0, buf1, biasf, flags, NN, 512, 512, PAD);
    // abstract1 -> buf1: hop1 (width 400 fused) + hop2
    spmm400_k<<<(NN + 3) / 4, 256, 0, stream>>>(row_ptr, edgesS,
                                                buf0 + 200, buf1 + 200, hop, nullptr);
    spmm200_k<<<(NN + 3) / 4, 256, 0, stream>>>(row_ptr, edgesS,
                                                hop, 200, buf1 + 400, PAD, nullptr);
    // V = abstract1 @ W2all -> buf0
    gemm128_k<<<NWG, 256, 0, stream>>>(buf1, w2t, buf0, nullptr, nullptr, 0, 0, NN, PAD, PAD, PAD);
    // stage-2 hops: read V (buf0 cols [200,600)); write buf1 cols [200,600)
    spmm400_k<<<(NN + 3) / 4, 256, 0, stream>>>(row_ptr, edgesS,
                                                buf0 + 200, buf1 + 200, hop, biasf + 800);
    spmm200_k<<<(NN + 3) / 4, 256, 0, stream>>>(row_ptr, edgesS,
                                                hop, 200, buf1 + 400, PAD, biasf + 1000);
    // node_emb + log_softmax fused -> d_out; gappy A: k<200 from buf0 (V0)
    fc64_k<<<(NN + 127) / 128, 256, 0, stream>>>(buf0, buf1, wfct, out_ne, out_pred,
                                                 biasf + 1280, NN, PAD, PAD);
}

// Round 7
// 1520.684 us; speedup vs baseline: 1.0752x; 1.0752x over previous
//
#include <hip/hip_runtime.h>

typedef unsigned short u16;
typedef unsigned int u32;
typedef __attribute__((ext_vector_type(8))) short short8;
typedef __attribute__((ext_vector_type(4))) float f32x4;
typedef __attribute__((ext_vector_type(4))) u32 u32x4;
typedef __attribute__((ext_vector_type(2))) u32 u32x2;

#define NN 100000
#define PAD 640

__device__ __forceinline__ float b2f(u16 u) {
    union { u32 i; float f; } v; v.i = ((u32)u) << 16; return v.f;
}
__device__ __forceinline__ u16 f2b(float f) {
    union { float f; u32 i; } v; v.f = f;
    u32 x = v.i;
    return (u16)((x + 0x7FFFu + ((x >> 16) & 1u)) >> 16);
}
__device__ __forceinline__ u32 pack2(float lo, float hi) {
    return (u32)f2b(lo) | ((u32)f2b(hi) << 16);
}
// read element i of a float tensor that is fp32 (f=1) or bf16 (f=0) on the wire
__device__ __forceinline__ float rdf(const void* p, size_t i, int f) {
    return f ? ((const float*)p)[i] : b2f(((const u16*)p)[i]);
}
// async global->LDS, 16B per lane; lptr must be wave-uniform
__device__ __forceinline__ void gload16(const u16* g, u16* l) {
    __builtin_amdgcn_global_load_lds(
        (const __attribute__((address_space(1))) void*)g,
        (__attribute__((address_space(3))) void*)l, 16, 0, 0);
}

// ---------------- dtype probes (wave-parallel) ----------------
__global__ void probe_k(const int* __restrict__ idx,
                        const void* avals, const void* feats, const void* W1,
                        const void* b1, const void* W2, const void* b2,
                        const void* Wfc, const void* bfc,
                        int* __restrict__ flags) {
    if (blockIdx.x != 0 || threadIdx.x >= 64) return;
    int lane = threadIdx.x;
    int v0 = idx[2 * lane + 1];
    int v1 = idx[2 * (lane + 64) + 1];
    int ok = (v0 == 0 && v1 == 0);
    int allz = __all(ok);
    if (lane == 0) flags[0] = allz ? 1 : 0;
    const void* ts[8] = {avals, feats, W1, b1, W2, b2, Wfc, bfc};
    const int ns[8] = {256, 256, 256, 128, 256, 128, 256, 32};
    for (int t = 0; t < 8; ++t) {
        const u16* p = (const u16*)ts[t];
        int n = ns[t], bad = 0;
        for (int i = lane; i < n; i += 64) {
            int e = (p[2 * i] >> 7) & 0xFF;
            if (e >= 133) bad++;
        }
        for (int off = 32; off; off >>= 1) bad += __shfl_xor(bad, off, 64);
        if (lane == 0) flags[1 + t] = (bad * 8 >= n) ? 1 : 0;
    }
}

__device__ __forceinline__ int load_row(const int* idx, int E, int f, int e) {
    return f ? idx[2 * e] : idx[e];
}
__device__ __forceinline__ int load_col(const int* idx, int E, int f, int e) {
    return f ? idx[2 * E + 2 * e] : idx[E + e];
}

// merged weight-transpose + bias conversion; blockIdx.y selects the job
// job4: bfc_adj[n] = bfc[n] + sum_{k<200} b2[0][k] * Wfc[k][n]  (copybias folded into FC)
__global__ void prep_k(const void* __restrict__ W1, const void* __restrict__ W2,
                       const void* __restrict__ Wfc,
                       const void* __restrict__ b1, const void* __restrict__ b2,
                       const void* __restrict__ bfc,
                       u16* __restrict__ w1t, u16* __restrict__ w2t,
                       u16* __restrict__ wfct, float* __restrict__ biasf,
                       const int* __restrict__ flags) {
    int i = blockIdx.x * 256 + threadIdx.x;
    int job = blockIdx.y;
    if (job == 0) {
        if (i >= 640 * 512) return;
        int n = i >> 9, k = i & 511;
        float v = 0.f;
        if (n < 600) {
            int ib = n / 200, c = n % 200;
            v = rdf(W1, (size_t)ib * 102400 + (size_t)k * 200 + c, flags[3]);
        }
        w1t[i] = f2b(v);
    } else if (job == 1) {
        if (i >= 640 * 640) return;
        int n = i / 640, k = i % 640;
        float v = 0.f;
        if (n < 600 && k < 600) {
            int ib = n / 200, c = n % 200;
            v = rdf(W2, (size_t)ib * 120000 + (size_t)k * 200 + c, flags[5]);
        }
        w2t[i] = f2b(v);
    } else if (job == 2) {
        if (i >= 64 * 640) return;
        int n = i / 640, k = i % 640;
        float v = 0.f;
        if (k < 600) v = rdf(Wfc, (size_t)k * 64 + n, flags[7]);
        wfct[i] = f2b(v);
    } else if (job == 3) {
        if (i < 600) biasf[i] = rdf(b1, i, flags[4]);
        else if (i < 1200) biasf[i] = rdf(b2, i - 600, flags[6]);
        else if (i < 1264) biasf[i] = rdf(bfc, i - 1200, flags[8]);
    } else {
        if (i >= 64) return;
        int fb2 = flags[6], fwf = flags[7];
        float s = rdf(bfc, i, flags[8]);
        for (int k = 0; k < 200; ++k)
            s += rdf(b2, k, fb2) * rdf(Wfc, (size_t)k * 64 + i, fwf);
        biasf[1280 + i] = s;
    }
}

// ---------------- CSR build (padded to 8 edges per row) ----------------
__device__ __forceinline__ int pad8(int c) { return (c + 7) & ~7; }

__global__ void count_k(const int* __restrict__ idx, int E, const int* __restrict__ flags,
                        int* __restrict__ counts) {
    int e = blockIdx.x * 256 + threadIdx.x;
    if (e >= E) return;
    int r = load_row(idx, E, flags[0], e);
    if ((u32)r >= NN) return;
    atomicAdd(&counts[r], 1);
}

__global__ void chunksum_k(const int* __restrict__ counts, int* __restrict__ chsum) {
    __shared__ int sm[256];
    int c = blockIdx.x, t = threadIdx.x;
    int base = c * 1024, s = 0;
    for (int i = t; i < 1024; i += 256) {
        int g = base + i;
        if (g < NN) s += pad8(counts[g]);
    }
    sm[t] = s; __syncthreads();
    for (int off = 128; off; off >>= 1) {
        if (t < off) sm[t] += sm[t + off];
        __syncthreads();
    }
    if (t == 0) chsum[c] = sm[0];
}

__global__ void chscan_k(const int* __restrict__ chsum, int nch, int* __restrict__ choff,
                         int* __restrict__ row_ptr, int E) {
    if (threadIdx.x == 0 && blockIdx.x == 0) {
        int run = 0;
        for (int c = 0; c < nch; ++c) { choff[c] = run; run += chsum[c]; }
        row_ptr[NN] = run;
    }
}

__global__ __launch_bounds__(1024) void scan_k(const int* __restrict__ counts,
                                               const int* __restrict__ choff,
                                               int* __restrict__ row_ptr,
                                               int* __restrict__ cursor) {
    __shared__ int sm[1024];
    int c = blockIdx.x, t = threadIdx.x;
    int g = c * 1024 + t;
    int v = (g < NN) ? pad8(counts[g]) : 0;
    sm[t] = v;
    __syncthreads();
    for (int off = 1; off < 1024; off <<= 1) {
        int add = (t >= off) ? sm[t - off] : 0;
        __syncthreads();
        sm[t] += add;
        __syncthreads();
    }
    if (g < NN) {
        int ex = choff[c] + sm[t] - v;
        row_ptr[g] = ex;
        cursor[g] = ex;
    }
}

// edges array: interleaved (col:int, val:f32) pairs
__global__ void scatter_k(const int* __restrict__ idx, const void* __restrict__ avals, int E,
                          const int* __restrict__ flags, int* __restrict__ cursor,
                          int* __restrict__ edges) {
    int e = blockIdx.x * 256 + threadIdx.x;
    if (e >= E) return;
    int f = flags[0];
    int r = load_row(idx, E, f, e);
    if ((u32)r >= NN) return;
    int c = load_col(idx, E, f, e);
    if ((u32)c >= NN) c = 0;
    int p = atomicAdd(&cursor[r], 1);
    edges[2 * p] = c;
    ((float*)edges)[2 * p + 1] = rdf(avals, e, flags[1]);
}

// fill padding slots with (col=0, val=0.0)
__global__ void padfill_k(const int* __restrict__ cursor, const int* __restrict__ row_ptr,
                          int* __restrict__ edges) {
    int r = blockIdx.x * 256 + threadIdx.x;
    if (r >= NN) return;
    int p = cursor[r], e = row_ptr[r + 1];
    for (; p < e; ++p) {
        edges[2 * p] = 0;
        ((float*)edges)[2 * p + 1] = 0.f;
    }
}

// ---------------- GEMM1: U = relu(feats @ W1all + b1), fused featconv+copypad ----------
// T3 minimum 2-phase pipeline: double-buffered LDS, ONE barrier per K-step,
// stage-before-compute. A (fp32/bf16 wire) reg-staged cooperatively (coalesced),
// loaded one full iteration ahead; B via gload16 issued before compute.
// Epilogue: C -> buf0 (all cols); side-copy to Cc=buf1 for col<200 and col>=600.
__global__ __launch_bounds__(256) void gemm1_k(
    const void* __restrict__ A, const u16* __restrict__ Bt,
    u16* __restrict__ C, u16* __restrict__ Cc,
    const float* __restrict__ bias, const int* __restrict__ flags,
    int M, int K, int lda, int ldc) {
    __shared__ u16 As[2][128 * 32];
    __shared__ u16 Bs[2][128 * 32];
    const int tid = threadIdx.x;
    const int wave = tid >> 6, lane = tid & 63;

    // bijective chunked XCD swizzle (m204)
    const int nwg = gridDim.x;
    const int q = nwg >> 3, r8 = nwg & 7;
    const int xcd = blockIdx.x & 7, lo = blockIdx.x >> 3;
    const int wg = (xcd < r8 ? xcd * (q + 1) : r8 * (q + 1) + (xcd - r8) * q) + lo;
    const int bmi = wg / 5, bni = wg - bmi * 5;
    const int bm = bmi * 128, bn = bni * 128;

    const int wrow = (wave >> 1) * 64, wcol = (wave & 1) * 64;
    const int l15 = lane & 15, l4 = lane >> 4;
    f32x4 acc[4][4] = {};

    const int ff = flags[2];
    const int c0 = wave * 2;
    const int rowA0 = c0 * 16 + (lane >> 2);
    const int rowA1 = rowA0 + 16;
    const int colE = (lane & 3) * 8;
    int gr0 = bm + rowA0; if (gr0 >= M) gr0 = M - 1;
    int gr1 = bm + rowA1; if (gr1 >= M) gr1 = M - 1;
    const float* a0f = (const float*)A + (size_t)gr0 * lda + colE;
    const float* a1f = (const float*)A + (size_t)gr1 * lda + colE;
    const u16* a0h = (const u16*)A + (size_t)gr0 * lda + colE;
    const u16* a1h = (const u16*)A + (size_t)gr1 * lda + colE;
    const u16* b0p = Bt + (size_t)(bn + rowA0) * K + colE;
    const u16* b1p = Bt + (size_t)(bn + rowA1) * K + colE;
    const int aoff0 = rowA0 * 32 + colE;   // linear staging dest (u16 elems)
    const int aoff1 = rowA1 * 32 + colE;

    // A staging registers (tile in flight)
    f32x4 x0a, x1a, x0b, x1b;   // fp32-wire path
    short8 h0, h1;              // bf16-wire path

    auto loadA = [&](int k0) {
        if (ff) {
            x0a = *(const f32x4*)(a0f + k0); x1a = *(const f32x4*)(a0f + k0 + 4);
            x0b = *(const f32x4*)(a1f + k0); x1b = *(const f32x4*)(a1f + k0 + 4);
        } else {
            h0 = *(const short8*)(a0h + k0);
            h1 = *(const short8*)(a1h + k0);
        }
    };
    auto writeA = [&](int buf) {
        short8 w0, w1;
        if (ff) {
#pragma unroll
            for (int t = 0; t < 4; ++t) {
                w0[t] = (short)f2b(x0a[t]); w0[t + 4] = (short)f2b(x1a[t]);
                w1[t] = (short)f2b(x0b[t]); w1[t + 4] = (short)f2b(x1b[t]);
            }
        } else { w0 = h0; w1 = h1; }
        *(short8*)&As[buf][aoff0] = w0;
        *(short8*)&As[buf][aoff1] = w1;
    };
    auto stageB = [&](int buf, int k0) {
        gload16(b0p + k0, &Bs[buf][c0 * 512]);
        gload16(b1p + k0, &Bs[buf][c0 * 512 + 512]);
    };

    const int NT = K >> 5;  // 16
    // prologue: stage tile 0, preload tile 1 into regs
    loadA(0);
    writeA(0);
    stageB(0, 0);
    loadA(32);
    __syncthreads();   // drains vmcnt(0) (B0 + A1-regs) and lgkm (A0 ds_writes)

    int cur = 0;
    for (int t = 0; t < NT; ++t) {
        if (t + 1 < NT) {
            // stage-before-compute: issue next-tile B loads + write next-tile A
            stageB(cur ^ 1, (t + 1) << 5);
            writeA(cur ^ 1);                 // regs valid (drained by last barrier)
            if (t + 2 < NT) loadA((t + 2) << 5);  // issue A loads for t+2
        }
        short8 af[4], bf[4];
#pragma unroll
        for (int tt = 0; tt < 4; ++tt) {
            af[tt] = *(const short8*)&As[cur][(wrow + tt * 16 + l15) * 32 + l4 * 8];
            bf[tt] = *(const short8*)&Bs[cur][(wcol + tt * 16 + l15) * 32 + l4 * 8];
        }
#pragma unroll
        for (int mi = 0; mi < 4; ++mi)
#pragma unroll
            for (int ni = 0; ni < 4; ++ni)
                acc[mi][ni] = __builtin_amdgcn_mfma_f32_16x16x32_bf16(
                    af[mi], bf[ni], acc[mi][ni], 0, 0, 0);
        __syncthreads();   // single drain per K-step: next tile ready
        cur ^= 1;
    }

#pragma unroll
    for (int mi = 0; mi < 4; ++mi)
#pragma unroll
        for (int ni = 0; ni < 4; ++ni)
#pragma unroll
            for (int r4 = 0; r4 < 4; ++r4) {
                int row = bm + wrow + mi * 16 + l4 * 4 + r4;
                int col = bn + wcol + ni * 16 + l15;
                if (row < M) {
                    float v = acc[mi][ni][r4];
                    if (col < 600) v += bias[col];
                    v = fmaxf(v, 0.0f);
                    u16 b = f2b(v);
                    C[(size_t)row * ldc + col] = b;
                    if (col < 200 || col >= 600)
                        Cc[(size_t)row * ldc + col] = b;
                }
            }
}

// ---------------- 128x128 MFMA GEMM with global_load_lds (m97 structure) ----------------
// C[M x N=640] = A[M x K] * Bt[640 x K]^T ; 1D grid, n-tile fastest, XCD swizzle.
__global__ __launch_bounds__(256) void gemm128_k(
    const u16* __restrict__ A, const u16* __restrict__ Bt,
    u16* __restrict__ C, float* __restrict__ Cf,
    const float* __restrict__ bias, int bias_n, int relu,
    int M, int K, int lda, int ldc) {
    __shared__ u16 As[128 * 32];
    __shared__ u16 Bs[128 * 32];
    const int tid = threadIdx.x;
    const int wave = tid >> 6, lane = tid & 63;

    const int nwg = gridDim.x;
    const int q = nwg >> 3, r8 = nwg & 7;
    const int xcd = blockIdx.x & 7, lo = blockIdx.x >> 3;
    const int wg = (xcd < r8 ? xcd * (q + 1) : r8 * (q + 1) + (xcd - r8) * q) + lo;
    const int bmi = wg / 5, bni = wg - bmi * 5;
    const int bm = bmi * 128, bn = bni * 128;

    const int wrow = (wave >> 1) * 64, wcol = (wave & 1) * 64;
    const int l15 = lane & 15, l4 = lane >> 4;
    f32x4 acc[4][4] = {};

    const int c0 = wave * 2;
    const int rowA0 = c0 * 16 + (lane >> 2);
    const int rowA1 = rowA0 + 16;
    const int colE = (lane & 3) * 8;
    int gr0 = bm + rowA0; if (gr0 >= M) gr0 = M - 1;
    int gr1 = bm + rowA1; if (gr1 >= M) gr1 = M - 1;
    const u16* a0p = A + (size_t)gr0 * lda + colE;
    const u16* a1p = A + (size_t)gr1 * lda + colE;
    const u16* b0p = Bt + (size_t)(bn + rowA0) * K + colE;
    const u16* b1p = Bt + (size_t)(bn + rowA1) * K + colE;
    u16* lA0 = As + c0 * 512;
    u16* lA1 = As + c0 * 512 + 512;
    u16* lB0 = Bs + c0 * 512;
    u16* lB1 = Bs + c0 * 512 + 512;

    for (int k0 = 0; k0 < K; k0 += 32) {
        __syncthreads();
        gload16(a0p + k0, lA0);
        gload16(a1p + k0, lA1);
        gload16(b0p + k0, lB0);
        gload16(b1p + k0, lB1);
        __syncthreads();
        short8 af[4], bf[4];
#pragma unroll
        for (int t = 0; t < 4; ++t) {
            af[t] = *(const short8*)&As[(wrow + t * 16 + l15) * 32 + l4 * 8];
            bf[t] = *(const short8*)&Bs[(wcol + t * 16 + l15) * 32 + l4 * 8];
        }
#pragma unroll
        for (int mi = 0; mi < 4; ++mi)
#pragma unroll
            for (int ni = 0; ni < 4; ++ni)
                acc[mi][ni] = __builtin_amdgcn_mfma_f32_16x16x32_bf16(
                    af[mi], bf[ni], acc[mi][ni], 0, 0, 0);
    }

#pragma unroll
    for (int mi = 0; mi < 4; ++mi)
#pragma unroll
        for (int ni = 0; ni < 4; ++ni)
#pragma unroll
            for (int r4 = 0; r4 < 4; ++r4) {
                int row = bm + wrow + mi * 16 + l4 * 4 + r4;
                int col = bn + wcol + ni * 16 + l15;
                if (row < M) {
                    float v = acc[mi][ni][r4];
                    if (bias && col < bias_n) v += bias[col];
                    if (relu) v = fmaxf(v, 0.0f);
                    if (C) C[(size_t)row * ldc + col] = f2b(v);
                    if (Cf) Cf[(size_t)row * ldc + col] = v;
                }
            }
}

// ---------------- fused FC (128x64 tile, gload16 staging) + log_softmax ----------------
// node_emb[M x 64] = concat_k(A0[:,0:200], A1[:,200:640]) @ Wfct[64 x K]^T + bias
__global__ __launch_bounds__(256) void fc64_k(
    const u16* __restrict__ A0, const u16* __restrict__ A1,
    const u16* __restrict__ Bt,
    float* __restrict__ out_ne, float* __restrict__ out_pred,
    const float* __restrict__ bias, int M, int K, int lda) {
    __shared__ __align__(16) char ldsbuf[128 * 64 * 4];  // 32 KB
    u16* As = (u16*)ldsbuf;             // 128x32 bf16 = 8 KB
    u16* Bs = (u16*)(ldsbuf + 8192);    // 64x32 bf16 = 4 KB
    float* smC = (float*)ldsbuf;        // 128x64 f32 (epilogue reuse)

    const int tid = threadIdx.x;
    const int wave = tid >> 6, lane = tid & 63;
    const int bm = blockIdx.x * 128;
    const int wrow = (wave >> 1) * 64, wcol = (wave & 1) * 32;
    const int l15 = lane & 15, l4 = lane >> 4;
    f32x4 acc[4][2] = {};

    const int colE = (lane & 3) * 8;
    int gr0 = bm + wave * 32 + (lane >> 2); if (gr0 >= M) gr0 = M - 1;
    int gr1 = bm + wave * 32 + 16 + (lane >> 2); if (gr1 >= M) gr1 = M - 1;
    const u16* a0p0 = A0 + (size_t)gr0 * lda + colE;
    const u16* a0p1 = A1 + (size_t)gr0 * lda + colE;
    const u16* a1p0 = A0 + (size_t)gr1 * lda + colE;
    const u16* a1p1 = A1 + (size_t)gr1 * lda + colE;
    const u16* bp = Bt + (size_t)(wave * 16 + (lane >> 2)) * K + colE;
    u16* lA0 = As + wave * 1024;
    u16* lA1 = As + wave * 1024 + 512;
    u16* lB = Bs + wave * 512;

    for (int k0 = 0; k0 < K; k0 += 32) {
        const bool in0 = (k0 + colE) < 200;  // 8-col granularity; 200 % 8 == 0
        const u16* pa0 = in0 ? a0p0 : a0p1;
        const u16* pa1 = in0 ? a1p0 : a1p1;
        __syncthreads();
        gload16(pa0 + k0, lA0);
        gload16(pa1 + k0, lA1);
        gload16(bp + k0, lB);
        __syncthreads();
        short8 af[4], bf[2];
#pragma unroll
        for (int t = 0; t < 4; ++t)
            af[t] = *(const short8*)&As[(wrow + t * 16 + l15) * 32 + l4 * 8];
#pragma unroll
        for (int t = 0; t < 2; ++t)
            bf[t] = *(const short8*)&Bs[(wcol + t * 16 + l15) * 32 + l4 * 8];
#pragma unroll
        for (int mi = 0; mi < 4; ++mi)
#pragma unroll
            for (int ni = 0; ni < 2; ++ni)
                acc[mi][ni] = __builtin_amdgcn_mfma_f32_16x16x32_bf16(
                    af[mi], bf[ni], acc[mi][ni], 0, 0, 0);
    }

    __syncthreads();  // all waves out of the K-loop before LDS reuse
#pragma unroll
    for (int mi = 0; mi < 4; ++mi)
#pragma unroll
        for (int ni = 0; ni < 2; ++ni)
#pragma unroll
            for (int r4 = 0; r4 < 4; ++r4) {
                int rl = wrow + mi * 16 + l4 * 4 + r4;
                int col = wcol + ni * 16 + l15;
                int row = bm + rl;
                float v = acc[mi][ni][r4] + bias[col];
                smC[rl * 64 + col] = v;
                if (row < M) out_ne[(size_t)row * 64 + col] = v;
            }
    __syncthreads();

    // log_softmax: 2 threads per row, 32 cols each (rotated to avoid bank conflicts)
    const int rl = tid >> 1, half = tid & 1;
    const int row = bm + rl;
    float vv[32];
#pragma unroll
    for (int k = 0; k < 32; ++k) {
        int c = half * 32 + ((k + rl) & 31);
        vv[k] = smC[rl * 64 + c];
    }
    float m = vv[0];
#pragma unroll
    for (int k = 1; k < 32; ++k) m = fmaxf(m, vv[k]);
    m = fmaxf(m, __shfl_xor(m, 1, 64));
    float s = 0.f;
#pragma unroll
    for (int k = 0; k < 32; ++k) s += expf(vv[k] - m);
    s += __shfl_xor(s, 1, 64);
    float lg = m + logf(s);
    if (row < M) {
#pragma unroll
        for (int k = 0; k < 32; ++k) {
            int c = half * 32 + ((k + rl) & 31);
            out_pred[(size_t)row * 64 + c] = vv[k] - lg;
        }
    }
}

// ---------------- fused width-400 spmm: one wave per row, 8 gathers in flight --------
__global__ __launch_bounds__(256) void spmm400_k(
    const int* __restrict__ row_ptr, const int* __restrict__ edges,
    const u16* __restrict__ X, u16* __restrict__ Y1, u16* __restrict__ Yt,
    const float* __restrict__ bias1) {
    int r = blockIdx.x * 4 + (threadIdx.x >> 6);
    if (r >= NN) return;
    int lane = threadIdx.x & 63;
    int s = row_ptr[r], e = row_ptr[r + 1];
    if (s < 0) s = 0;
    if (e < s) e = s;
    float a[8] = {0.f, 0.f, 0.f, 0.f, 0.f, 0.f, 0.f, 0.f};
    const bool act = lane < 50;
    const u32* xl = (const u32*)X + lane * 4;
    for (int i = s; i < e; i += 8) {
        int cc[8]; float vv[8];
#pragma unroll
        for (int j = 0; j < 4; ++j) {
            u32x4 p = *(const u32x4*)(edges + 2 * (size_t)(i + 2 * j));
            union { u32 u; float f; } w0, w1;
            cc[2 * j] = (int)p[0];     w0.u = p[1];
            cc[2 * j + 1] = (int)p[2]; w1.u = p[3];
            vv[2 * j] = w0.f; vv[2 * j + 1] = w1.f;
        }
        if (act) {
            u32x4 g[8];
#pragma unroll
            for (int j = 0; j < 8; ++j) {
                u32 c = (u32)cc[j]; if (c >= NN) c = 0;
                g[j] = *(const u32x4*)(xl + (size_t)c * 320);
            }
#pragma unroll
            for (int j = 0; j < 8; ++j) {
                float v = vv[j];
#pragma unroll
                for (int q = 0; q < 4; ++q) {
                    union { u32 i; float f; } lo, hi;
                    lo.i = g[j][q] << 16; hi.i = g[j][q] & 0xffff0000u;
                    a[2 * q] = fmaf(v, lo.f, a[2 * q]);
                    a[2 * q + 1] = fmaf(v, hi.f, a[2 * q + 1]);
                }
            }
        }
    }
    if (bias1 && lane < 25) {
#pragma unroll
        for (int q = 0; q < 8; ++q) a[q] += bias1[lane * 8 + q];
    }
    u32x4 o;
    o[0] = pack2(a[0], a[1]); o[1] = pack2(a[2], a[3]);
    o[2] = pack2(a[4], a[5]); o[3] = pack2(a[6], a[7]);
    if (lane < 25) {
        *(u32x4*)((u32*)Y1 + (size_t)r * 320 + lane * 4) = o;
    } else if (lane < 50) {
        *(u32x4*)((u32*)Yt + (size_t)r * 100 + (lane - 25) * 4) = o;
    }
}

// ---------------- width-200 spmm: one wave per row, 8 gathers in flight --------------
__global__ __launch_bounds__(256) void spmm200_k(
    const int* __restrict__ row_ptr, const int* __restrict__ edges,
    const u16* __restrict__ X, int ldx,
    u16* __restrict__ Y, int ldy,
    const float* __restrict__ bias) {
    int r = blockIdx.x * 4 + (threadIdx.x >> 6);
    if (r >= NN) return;
    int lane = threadIdx.x & 63;
    int s = row_ptr[r], e = row_ptr[r + 1];
    if (s < 0) s = 0;
    if (e < s) e = s;
    float a[4] = {0.f, 0.f, 0.f, 0.f};
    const bool act = lane < 50;
    const int ldxw = ldx >> 1, ldyw = ldy >> 1;
    const u32* xl = (const u32*)X + lane * 2;
    for (int i = s; i < e; i += 8) {
        int cc[8]; float vv[8];
#pragma unroll
        for (int j = 0; j < 4; ++j) {
            u32x4 p = *(const u32x4*)(edges + 2 * (size_t)(i + 2 * j));
            union { u32 u; float f; } w0, w1;
            cc[2 * j] = (int)p[0];     w0.u = p[1];
            cc[2 * j + 1] = (int)p[2]; w1.u = p[3];
            vv[2 * j] = w0.f; vv[2 * j + 1] = w1.f;
        }
        if (act) {
            u32x2 g[8];
#pragma unroll
            for (int j = 0; j < 8; ++j) {
                u32 c = (u32)cc[j]; if (c >= NN) c = 0;
                g[j] = *(const u32x2*)(xl + (size_t)c * ldxw);
            }
#pragma unroll
            for (int j = 0; j < 8; ++j) {
                float v = vv[j];
#pragma unroll
                for (int q = 0; q < 2; ++q) {
                    union { u32 i; float f; } lo, hi;
                    lo.i = g[j][q] << 16; hi.i = g[j][q] & 0xffff0000u;
                    a[2 * q] = fmaf(v, lo.f, a[2 * q]);
                    a[2 * q + 1] = fmaf(v, hi.f, a[2 * q + 1]);
                }
            }
        }
    }
    if (bias && act) {
#pragma unroll
        for (int q = 0; q < 4; ++q) a[q] += bias[lane * 4 + q];
    }
    if (act) {
        u32x2 o;
        o[0] = pack2(a[0], a[1]); o[1] = pack2(a[2], a[3]);
        *(u32x2*)((u32*)Y + (size_t)r * ldyw + lane * 2) = o;
    }
}

extern "C" void kernel_launch(void* const* d_in, const int* in_sizes, int n_in,
                              void* d_out, int out_size, void* d_ws, size_t ws_size,
                              hipStream_t stream) {
    const int* adj_idx = (const int*)d_in[0];
    const void* adj_vals = d_in[1];
    const void* feats = d_in[2];
    const void* W1 = d_in[3];
    const void* b1 = d_in[4];
    const void* W2 = d_in[5];
    const void* b2 = d_in[6];
    const void* Wfc = d_in[7];
    const void* bfc = d_in[8];
    const int E = in_sizes[1];
    (void)n_in; (void)out_size; (void)ws_size;

    char* ws = (char*)d_ws;
    size_t off = 0;
    auto alloc = [&](size_t b) { size_t o = off; off += (b + 255) & ~(size_t)255; return o; };
    u16* buf0 = (u16*)(ws + alloc((size_t)NN * PAD * 2));   // U, then V
    u16* buf1 = (u16*)(ws + alloc((size_t)NN * PAD * 2));   // abstract1, stage-2 hops
    u16* hop = (u16*)(ws + alloc((size_t)NN * 200 * 2));
    u16* w1t = (u16*)(ws + alloc((size_t)640 * 512 * 2));
    u16* w2t = (u16*)(ws + alloc((size_t)640 * 640 * 2));
    u16* wfct = (u16*)(ws + alloc((size_t)64 * 640 * 2));
    float* biasf = (float*)(ws + alloc(1344 * 4));  // b1|b2|bfc|bfc_adj(1280+)
    int* counts = (int*)(ws + alloc((size_t)NN * 4));
    int* cursor = (int*)(ws + alloc((size_t)NN * 4));
    int* row_ptr = (int*)(ws + alloc((size_t)(NN + 1) * 4));
    int* chsum = (int*)(ws + alloc(4096));
    int* choff = (int*)(ws + alloc(4096));
    int* flags = (int*)(ws + alloc(256));
    // interleaved (col, val) pairs; padded to multiple of 8 per row
    int* edgesS = (int*)(ws + alloc(((size_t)E + 8 * (size_t)NN) * 8));

    float* out_ne = (float*)d_out;              // fp32 node_emb
    float* out_pred = out_ne + (size_t)NN * 64; // fp32 log-softmax

    // probes + weight prep
    probe_k<<<1, 64, 0, stream>>>(adj_idx, adj_vals, feats, W1, b1, W2, b2, Wfc, bfc, flags);
    dim3 gp(1600, 5);
    prep_k<<<gp, 256, 0, stream>>>(W1, W2, Wfc, b1, b2, bfc, w1t, w2t, wfct, biasf, flags);

    // CSR build (padded to 8 edges/row)
    hipMemsetAsync(counts, 0, NN * 4, stream);
    count_k<<<(E + 255) / 256, 256, 0, stream>>>(adj_idx, E, flags, counts);
    const int NCH = (NN + 1023) / 1024;  // 98
    chunksum_k<<<NCH, 256, 0, stream>>>(counts, chsum);
    chscan_k<<<1, 64, 0, stream>>>(chsum, NCH, choff, row_ptr, E);
    scan_k<<<NCH, 1024, 0, stream>>>(counts, choff, row_ptr, cursor);
    scatter_k<<<(E + 255) / 256, 256, 0, stream>>>(adj_idx, adj_vals, E, flags, cursor, edgesS);
    padfill_k<<<(NN + 255) / 256, 256, 0, stream>>>(cursor, row_ptr, edgesS);

    const int NWG = ((NN + 127) / 128) * 5;  // 782 M-tiles x 5 N-tiles = 3910
    // U = relu(feats @ W1all + b1) -> buf0; side-copy block0 + zero pad -> buf1
    gemm1_k<<<NWG, 256, 0, stream>>>(feats, w1t, buf0, buf1, biasf, flags, NN, 512, 512, PAD);
    // abstract1 -> buf1: hop1 (width 400 fused) + hop2
    spmm400_k<<<(NN + 3) / 4, 256, 0, stream>>>(row_ptr, edgesS,
                                                buf0 + 200, buf1 + 200, hop, nullptr);
    spmm200_k<<<(NN + 3) / 4, 256, 0, stream>>>(row_ptr, edgesS,
                                                hop, 200, buf1 + 400, PAD, nullptr);
    // V = abstract1 @ W2all -> buf0
    gemm128_k<<<NWG, 256, 0, stream>>>(buf1, w2t, buf0, nullptr, nullptr, 0, 0, NN, PAD, PAD, PAD);
    // stage-2 hops: read V (buf0 cols [200,600)); write buf1 cols [200,600)
    spmm400_k<<<(NN + 3) / 4, 256, 0, stream>>>(row_ptr, edgesS,
                                                buf0 + 200, buf1 + 200, hop, biasf + 800);
    spmm200_k<<<(NN + 3) / 4, 256, 0, stream>>>(row_ptr, edgesS,
                                                hop, 200, buf1 + 400, PAD, biasf + 1000);
    // node_emb + log_softmax fused -> d_out; gappy A: k<200 from buf0 (V0)
    fc64_k<<<(NN + 127) / 128, 256, 0, stream>>>(buf0, buf1, wfct, out_ne, out_pred,
                                                 biasf + 1280, NN, PAD, PAD);
}

// Round 8
// 1481.045 us; speedup vs baseline: 1.1040x; 1.0268x over previous
//
#include <hip/hip_runtime.h>

typedef unsigned short u16;
typedef unsigned int u32;
typedef __attribute__((ext_vector_type(8))) short short8;
typedef __attribute__((ext_vector_type(4))) float f32x4;
typedef __attribute__((ext_vector_type(4))) u32 u32x4;
typedef __attribute__((ext_vector_type(2))) u32 u32x2;

#define NN 100000
#define PAD 640

__device__ __forceinline__ float b2f(u16 u) {
    union { u32 i; float f; } v; v.i = ((u32)u) << 16; return v.f;
}
__device__ __forceinline__ u16 f2b(float f) {
    union { float f; u32 i; } v; v.f = f;
    u32 x = v.i;
    return (u16)((x + 0x7FFFu + ((x >> 16) & 1u)) >> 16);
}
__device__ __forceinline__ u32 pack2(float lo, float hi) {
    return (u32)f2b(lo) | ((u32)f2b(hi) << 16);
}
// read element i of a float tensor that is fp32 (f=1) or bf16 (f=0) on the wire
__device__ __forceinline__ float rdf(const void* p, size_t i, int f) {
    return f ? ((const float*)p)[i] : b2f(((const u16*)p)[i]);
}
// async global->LDS, 16B per lane; lptr must be wave-uniform
__device__ __forceinline__ void gload16(const u16* g, u16* l) {
    __builtin_amdgcn_global_load_lds(
        (const __attribute__((address_space(1))) void*)g,
        (__attribute__((address_space(3))) void*)l, 16, 0, 0);
}

// ---------------- dtype probes (wave-parallel) ----------------
__global__ void probe_k(const int* __restrict__ idx,
                        const void* avals, const void* feats, const void* W1,
                        const void* b1, const void* W2, const void* b2,
                        const void* Wfc, const void* bfc,
                        int* __restrict__ flags) {
    if (blockIdx.x != 0 || threadIdx.x >= 64) return;
    int lane = threadIdx.x;
    int v0 = idx[2 * lane + 1];
    int v1 = idx[2 * (lane + 64) + 1];
    int ok = (v0 == 0 && v1 == 0);
    int allz = __all(ok);
    if (lane == 0) flags[0] = allz ? 1 : 0;
    const void* ts[8] = {avals, feats, W1, b1, W2, b2, Wfc, bfc};
    const int ns[8] = {256, 256, 256, 128, 256, 128, 256, 32};
    for (int t = 0; t < 8; ++t) {
        const u16* p = (const u16*)ts[t];
        int n = ns[t], bad = 0;
        for (int i = lane; i < n; i += 64) {
            int e = (p[2 * i] >> 7) & 0xFF;
            if (e >= 133) bad++;
        }
        for (int off = 32; off; off >>= 1) bad += __shfl_xor(bad, off, 64);
        if (lane == 0) flags[1 + t] = (bad * 8 >= n) ? 1 : 0;
    }
}

__device__ __forceinline__ int load_row(const int* idx, int E, int f, int e) {
    return f ? idx[2 * e] : idx[e];
}
__device__ __forceinline__ int load_col(const int* idx, int E, int f, int e) {
    return f ? idx[2 * E + 2 * e] : idx[E + e];
}

// merged weight-transpose + bias conversion; blockIdx.y selects the job
// job4: bfc_adj[n] = bfc[n] + sum_{k<200} b2[0][k] * Wfc[k][n]  (copybias folded into FC)
__global__ void prep_k(const void* __restrict__ W1, const void* __restrict__ W2,
                       const void* __restrict__ Wfc,
                       const void* __restrict__ b1, const void* __restrict__ b2,
                       const void* __restrict__ bfc,
                       u16* __restrict__ w1t, u16* __restrict__ w2t,
                       u16* __restrict__ wfct, float* __restrict__ biasf,
                       const int* __restrict__ flags) {
    int i = blockIdx.x * 256 + threadIdx.x;
    int job = blockIdx.y;
    if (job == 0) {
        if (i >= 640 * 512) return;
        int n = i >> 9, k = i & 511;
        float v = 0.f;
        if (n < 600) {
            int ib = n / 200, c = n % 200;
            v = rdf(W1, (size_t)ib * 102400 + (size_t)k * 200 + c, flags[3]);
        }
        w1t[i] = f2b(v);
    } else if (job == 1) {
        if (i >= 640 * 640) return;
        int n = i / 640, k = i % 640;
        float v = 0.f;
        if (n < 600 && k < 600) {
            int ib = n / 200, c = n % 200;
            v = rdf(W2, (size_t)ib * 120000 + (size_t)k * 200 + c, flags[5]);
        }
        w2t[i] = f2b(v);
    } else if (job == 2) {
        if (i >= 64 * 640) return;
        int n = i / 640, k = i % 640;
        float v = 0.f;
        if (k < 600) v = rdf(Wfc, (size_t)k * 64 + n, flags[7]);
        wfct[i] = f2b(v);
    } else if (job == 3) {
        if (i < 600) biasf[i] = rdf(b1, i, flags[4]);
        else if (i < 1200) biasf[i] = rdf(b2, i - 600, flags[6]);
        else if (i < 1264) biasf[i] = rdf(bfc, i - 1200, flags[8]);
    } else {
        if (i >= 64) return;
        int fb2 = flags[6], fwf = flags[7];
        float s = rdf(bfc, i, flags[8]);
        for (int k = 0; k < 200; ++k)
            s += rdf(b2, k, fb2) * rdf(Wfc, (size_t)k * 64 + i, fwf);
        biasf[1280 + i] = s;
    }
}

// ---------------- CSR build (padded to 8 edges per row) ----------------
__device__ __forceinline__ int pad8(int c) { return (c + 7) & ~7; }

__global__ void count_k(const int* __restrict__ idx, int E, const int* __restrict__ flags,
                        int* __restrict__ counts) {
    int e = blockIdx.x * 256 + threadIdx.x;
    if (e >= E) return;
    int r = load_row(idx, E, flags[0], e);
    if ((u32)r >= NN) return;
    atomicAdd(&counts[r], 1);
}

__global__ void chunksum_k(const int* __restrict__ counts, int* __restrict__ chsum) {
    __shared__ int sm[256];
    int c = blockIdx.x, t = threadIdx.x;
    int base = c * 1024, s = 0;
    for (int i = t; i < 1024; i += 256) {
        int g = base + i;
        if (g < NN) s += pad8(counts[g]);
    }
    sm[t] = s; __syncthreads();
    for (int off = 128; off; off >>= 1) {
        if (t < off) sm[t] += sm[t + off];
        __syncthreads();
    }
    if (t == 0) chsum[c] = sm[0];
}

__global__ void chscan_k(const int* __restrict__ chsum, int nch, int* __restrict__ choff,
                         int* __restrict__ row_ptr, int E) {
    if (threadIdx.x == 0 && blockIdx.x == 0) {
        int run = 0;
        for (int c = 0; c < nch; ++c) { choff[c] = run; run += chsum[c]; }
        row_ptr[NN] = run;
    }
}

__global__ __launch_bounds__(1024) void scan_k(const int* __restrict__ counts,
                                               const int* __restrict__ choff,
                                               int* __restrict__ row_ptr,
                                               int* __restrict__ cursor) {
    __shared__ int sm[1024];
    int c = blockIdx.x, t = threadIdx.x;
    int g = c * 1024 + t;
    int v = (g < NN) ? pad8(counts[g]) : 0;
    sm[t] = v;
    __syncthreads();
    for (int off = 1; off < 1024; off <<= 1) {
        int add = (t >= off) ? sm[t - off] : 0;
        __syncthreads();
        sm[t] += add;
        __syncthreads();
    }
    if (g < NN) {
        int ex = choff[c] + sm[t] - v;
        row_ptr[g] = ex;
        cursor[g] = ex;
    }
}

// edges array: interleaved (col:int, val:f32) pairs
__global__ void scatter_k(const int* __restrict__ idx, const void* __restrict__ avals, int E,
                          const int* __restrict__ flags, int* __restrict__ cursor,
                          int* __restrict__ edges) {
    int e = blockIdx.x * 256 + threadIdx.x;
    if (e >= E) return;
    int f = flags[0];
    int r = load_row(idx, E, f, e);
    if ((u32)r >= NN) return;
    int c = load_col(idx, E, f, e);
    if ((u32)c >= NN) c = 0;
    int p = atomicAdd(&cursor[r], 1);
    edges[2 * p] = c;
    ((float*)edges)[2 * p + 1] = rdf(avals, e, flags[1]);
}

// fill padding slots with (col=0, val=0.0)
__global__ void padfill_k(const int* __restrict__ cursor, const int* __restrict__ row_ptr,
                          int* __restrict__ edges) {
    int r = blockIdx.x * 256 + threadIdx.x;
    if (r >= NN) return;
    int p = cursor[r], e = row_ptr[r + 1];
    for (; p < e; ++p) {
        edges[2 * p] = 0;
        ((float*)edges)[2 * p + 1] = 0.f;
    }
}

// ---------------- GEMM1: U = relu(feats @ W1all + b1), 256x128 tile, 8 waves ---------
// A = feats (fp32/bf16 wire), reg-staged with cvt; B via gload16 issued FIRST so
// A-latency and B-latency overlap under one barrier drain. 2x MFMA per barrier pair
// vs the 128x128 version (short-K amortization). Epilogue: C->buf0 all cols;
// side-copy to Cc=buf1 for col<200 (abstract1 block0) and col>=600 (zeros).
__global__ __launch_bounds__(512) void gemm1_k(
    const void* __restrict__ A, const u16* __restrict__ Bt,
    u16* __restrict__ C, u16* __restrict__ Cc,
    const float* __restrict__ bias, const int* __restrict__ flags,
    int M, int K, int lda, int ldc) {
    __shared__ u16 As[256 * 32];   // 16 KB
    __shared__ u16 Bs[128 * 32];   // 8 KB
    const int tid = threadIdx.x;
    const int wave = tid >> 6, lane = tid & 63;

    // bijective chunked XCD swizzle (m204)
    const int nwg = gridDim.x;
    const int q = nwg >> 3, r8 = nwg & 7;
    const int xcd = blockIdx.x & 7, lo = blockIdx.x >> 3;
    const int wg = (xcd < r8 ? xcd * (q + 1) : r8 * (q + 1) + (xcd - r8) * q) + lo;
    const int bmi = wg / 5, bni = wg - bmi * 5;
    const int bm = bmi * 256, bn = bni * 128;

    const int wrow = (wave >> 1) * 64, wcol = (wave & 1) * 64;
    const int l15 = lane & 15, l4 = lane >> 4;
    f32x4 acc[4][4] = {};

    const int ff = flags[2];
    // A staging: wave w covers rows 32w..32w+31 (2 chunks of 16 rows)
    const int rowA0 = wave * 32 + (lane >> 2);
    const int rowA1 = rowA0 + 16;
    const int colE = (lane & 3) * 8;
    int gr0 = bm + rowA0; if (gr0 >= M) gr0 = M - 1;
    int gr1 = bm + rowA1; if (gr1 >= M) gr1 = M - 1;
    const float* a0f = (const float*)A + (size_t)gr0 * lda + colE;
    const float* a1f = (const float*)A + (size_t)gr1 * lda + colE;
    const u16* a0h = (const u16*)A + (size_t)gr0 * lda + colE;
    const u16* a1h = (const u16*)A + (size_t)gr1 * lda + colE;
    const int aoff0 = rowA0 * 32 + colE;
    const int aoff1 = rowA1 * 32 + colE;
    // B staging: wave w covers rows 16w..16w+15
    const int rowB = wave * 16 + (lane >> 2);
    const u16* bp = Bt + (size_t)(bn + rowB) * K + colE;
    u16* lB = Bs + wave * 512;

    for (int k0 = 0; k0 < K; k0 += 32) {
        __syncthreads();              // WAR on As/Bs (regs only outstanding)
        gload16(bp + k0, lB);         // B async first (overlaps A reg-loads)
        short8 w0, w1;
        if (ff) {
            f32x4 x0 = *(const f32x4*)(a0f + k0);
            f32x4 x1 = *(const f32x4*)(a0f + k0 + 4);
            f32x4 y0 = *(const f32x4*)(a1f + k0);
            f32x4 y1 = *(const f32x4*)(a1f + k0 + 4);
#pragma unroll
            for (int t = 0; t < 4; ++t) {
                w0[t] = (short)f2b(x0[t]); w0[t + 4] = (short)f2b(x1[t]);
                w1[t] = (short)f2b(y0[t]); w1[t + 4] = (short)f2b(y1[t]);
            }
        } else {
            w0 = *(const short8*)(a0h + k0);
            w1 = *(const short8*)(a1h + k0);
        }
        *(short8*)&As[aoff0] = w0;
        *(short8*)&As[aoff1] = w1;
        __syncthreads();              // single drain: max(A-lat, B-lat)
        short8 af[4], bf[4];
#pragma unroll
        for (int t = 0; t < 4; ++t) {
            af[t] = *(const short8*)&As[(wrow + t * 16 + l15) * 32 + l4 * 8];
            bf[t] = *(const short8*)&Bs[(wcol + t * 16 + l15) * 32 + l4 * 8];
        }
#pragma unroll
        for (int mi = 0; mi < 4; ++mi)
#pragma unroll
            for (int ni = 0; ni < 4; ++ni)
                acc[mi][ni] = __builtin_amdgcn_mfma_f32_16x16x32_bf16(
                    af[mi], bf[ni], acc[mi][ni], 0, 0, 0);
    }

#pragma unroll
    for (int mi = 0; mi < 4; ++mi)
#pragma unroll
        for (int ni = 0; ni < 4; ++ni)
#pragma unroll
            for (int r4 = 0; r4 < 4; ++r4) {
                int row = bm + wrow + mi * 16 + l4 * 4 + r4;
                int col = bn + wcol + ni * 16 + l15;
                if (row < M) {
                    float v = acc[mi][ni][r4];
                    if (col < 600) v += bias[col];
                    v = fmaxf(v, 0.0f);
                    u16 b = f2b(v);
                    C[(size_t)row * ldc + col] = b;
                    if (col < 200 || col >= 600)
                        Cc[(size_t)row * ldc + col] = b;
                }
            }
}

// ---------------- GEMM2: V = abstract1 @ W2all, 256x128 tile, 8 waves, all-gload16 ---
__global__ __launch_bounds__(512) void gemm2_k(
    const u16* __restrict__ A, const u16* __restrict__ Bt,
    u16* __restrict__ C, int M, int K, int lda, int ldc) {
    __shared__ u16 As[256 * 32];   // 16 KB
    __shared__ u16 Bs[128 * 32];   // 8 KB
    const int tid = threadIdx.x;
    const int wave = tid >> 6, lane = tid & 63;

    const int nwg = gridDim.x;
    const int q = nwg >> 3, r8 = nwg & 7;
    const int xcd = blockIdx.x & 7, lo = blockIdx.x >> 3;
    const int wg = (xcd < r8 ? xcd * (q + 1) : r8 * (q + 1) + (xcd - r8) * q) + lo;
    const int bmi = wg / 5, bni = wg - bmi * 5;
    const int bm = bmi * 256, bn = bni * 128;

    const int wrow = (wave >> 1) * 64, wcol = (wave & 1) * 64;
    const int l15 = lane & 15, l4 = lane >> 4;
    f32x4 acc[4][4] = {};

    // A staging: wave w covers chunks 2w,2w+1 (rows 32w..32w+31)
    const int rowA0 = wave * 32 + (lane >> 2);
    const int rowA1 = rowA0 + 16;
    const int colE = (lane & 3) * 8;
    int gr0 = bm + rowA0; if (gr0 >= M) gr0 = M - 1;
    int gr1 = bm + rowA1; if (gr1 >= M) gr1 = M - 1;
    const u16* a0p = A + (size_t)gr0 * lda + colE;
    const u16* a1p = A + (size_t)gr1 * lda + colE;
    u16* lA0 = As + wave * 1024;
    u16* lA1 = As + wave * 1024 + 512;
    // B staging: wave w covers rows 16w..16w+15
    const int rowB = wave * 16 + (lane >> 2);
    const u16* bp = Bt + (size_t)(bn + rowB) * K + colE;
    u16* lB = Bs + wave * 512;

    for (int k0 = 0; k0 < K; k0 += 32) {
        __syncthreads();
        gload16(a0p + k0, lA0);
        gload16(a1p + k0, lA1);
        gload16(bp + k0, lB);
        __syncthreads();
        short8 af[4], bf[4];
#pragma unroll
        for (int t = 0; t < 4; ++t) {
            af[t] = *(const short8*)&As[(wrow + t * 16 + l15) * 32 + l4 * 8];
            bf[t] = *(const short8*)&Bs[(wcol + t * 16 + l15) * 32 + l4 * 8];
        }
#pragma unroll
        for (int mi = 0; mi < 4; ++mi)
#pragma unroll
            for (int ni = 0; ni < 4; ++ni)
                acc[mi][ni] = __builtin_amdgcn_mfma_f32_16x16x32_bf16(
                    af[mi], bf[ni], acc[mi][ni], 0, 0, 0);
    }

#pragma unroll
    for (int mi = 0; mi < 4; ++mi)
#pragma unroll
        for (int ni = 0; ni < 4; ++ni)
#pragma unroll
            for (int r4 = 0; r4 < 4; ++r4) {
                int row = bm + wrow + mi * 16 + l4 * 4 + r4;
                int col = bn + wcol + ni * 16 + l15;
                if (row < M)
                    C[(size_t)row * ldc + col] = f2b(acc[mi][ni][r4]);
            }
}

// ---------------- fused FC (128x64 tile, gload16 staging) + log_softmax ----------------
// node_emb[M x 64] = concat_k(A0[:,0:200], A1[:,200:640]) @ Wfct[64 x K]^T + bias
__global__ __launch_bounds__(256) void fc64_k(
    const u16* __restrict__ A0, const u16* __restrict__ A1,
    const u16* __restrict__ Bt,
    float* __restrict__ out_ne, float* __restrict__ out_pred,
    const float* __restrict__ bias, int M, int K, int lda) {
    __shared__ __align__(16) char ldsbuf[128 * 64 * 4];  // 32 KB
    u16* As = (u16*)ldsbuf;             // 128x32 bf16 = 8 KB
    u16* Bs = (u16*)(ldsbuf + 8192);    // 64x32 bf16 = 4 KB
    float* smC = (float*)ldsbuf;        // 128x64 f32 (epilogue reuse)

    const int tid = threadIdx.x;
    const int wave = tid >> 6, lane = tid & 63;
    const int bm = blockIdx.x * 128;
    const int wrow = (wave >> 1) * 64, wcol = (wave & 1) * 32;
    const int l15 = lane & 15, l4 = lane >> 4;
    f32x4 acc[4][2] = {};

    const int colE = (lane & 3) * 8;
    int gr0 = bm + wave * 32 + (lane >> 2); if (gr0 >= M) gr0 = M - 1;
    int gr1 = bm + wave * 32 + 16 + (lane >> 2); if (gr1 >= M) gr1 = M - 1;
    const u16* a0p0 = A0 + (size_t)gr0 * lda + colE;
    const u16* a0p1 = A1 + (size_t)gr0 * lda + colE;
    const u16* a1p0 = A0 + (size_t)gr1 * lda + colE;
    const u16* a1p1 = A1 + (size_t)gr1 * lda + colE;
    const u16* bp = Bt + (size_t)(wave * 16 + (lane >> 2)) * K + colE;
    u16* lA0 = As + wave * 1024;
    u16* lA1 = As + wave * 1024 + 512;
    u16* lB = Bs + wave * 512;

    for (int k0 = 0; k0 < K; k0 += 32) {
        const bool in0 = (k0 + colE) < 200;  // 8-col granularity; 200 % 8 == 0
        const u16* pa0 = in0 ? a0p0 : a0p1;
        const u16* pa1 = in0 ? a1p0 : a1p1;
        __syncthreads();
        gload16(pa0 + k0, lA0);
        gload16(pa1 + k0, lA1);
        gload16(bp + k0, lB);
        __syncthreads();
        short8 af[4], bf[2];
#pragma unroll
        for (int t = 0; t < 4; ++t)
            af[t] = *(const short8*)&As[(wrow + t * 16 + l15) * 32 + l4 * 8];
#pragma unroll
        for (int t = 0; t < 2; ++t)
            bf[t] = *(const short8*)&Bs[(wcol + t * 16 + l15) * 32 + l4 * 8];
#pragma unroll
        for (int mi = 0; mi < 4; ++mi)
#pragma unroll
            for (int ni = 0; ni < 2; ++ni)
                acc[mi][ni] = __builtin_amdgcn_mfma_f32_16x16x32_bf16(
                    af[mi], bf[ni], acc[mi][ni], 0, 0, 0);
    }

    __syncthreads();  // all waves out of the K-loop before LDS reuse
#pragma unroll
    for (int mi = 0; mi < 4; ++mi)
#pragma unroll
        for (int ni = 0; ni < 2; ++ni)
#pragma unroll
            for (int r4 = 0; r4 < 4; ++r4) {
                int rl = wrow + mi * 16 + l4 * 4 + r4;
                int col = wcol + ni * 16 + l15;
                int row = bm + rl;
                float v = acc[mi][ni][r4] + bias[col];
                smC[rl * 64 + col] = v;
                if (row < M) out_ne[(size_t)row * 64 + col] = v;
            }
    __syncthreads();

    // log_softmax: 2 threads per row, 32 cols each (rotated to avoid bank conflicts)
    const int rl = tid >> 1, half = tid & 1;
    const int row = bm + rl;
    float vv[32];
#pragma unroll
    for (int k = 0; k < 32; ++k) {
        int c = half * 32 + ((k + rl) & 31);
        vv[k] = smC[rl * 64 + c];
    }
    float m = vv[0];
#pragma unroll
    for (int k = 1; k < 32; ++k) m = fmaxf(m, vv[k]);
    m = fmaxf(m, __shfl_xor(m, 1, 64));
    float s = 0.f;
#pragma unroll
    for (int k = 0; k < 32; ++k) s += expf(vv[k] - m);
    s += __shfl_xor(s, 1, 64);
    float lg = m + logf(s);
    if (row < M) {
#pragma unroll
        for (int k = 0; k < 32; ++k) {
            int c = half * 32 + ((k + rl) & 31);
            out_pred[(size_t)row * 64 + c] = vv[k] - lg;
        }
    }
}

// ---------------- fused width-400 spmm: one wave per row, 8 gathers in flight --------
__global__ __launch_bounds__(256) void spmm400_k(
    const int* __restrict__ row_ptr, const int* __restrict__ edges,
    const u16* __restrict__ X, u16* __restrict__ Y1, u16* __restrict__ Yt,
    const float* __restrict__ bias1) {
    int r = blockIdx.x * 4 + (threadIdx.x >> 6);
    if (r >= NN) return;
    int lane = threadIdx.x & 63;
    int s = row_ptr[r], e = row_ptr[r + 1];
    if (s < 0) s = 0;
    if (e < s) e = s;
    float a[8] = {0.f, 0.f, 0.f, 0.f, 0.f, 0.f, 0.f, 0.f};
    const bool act = lane < 50;
    const u32* xl = (const u32*)X + lane * 4;
    for (int i = s; i < e; i += 8) {
        int cc[8]; float vv[8];
#pragma unroll
        for (int j = 0; j < 4; ++j) {
            u32x4 p = *(const u32x4*)(edges + 2 * (size_t)(i + 2 * j));
            union { u32 u; float f; } w0, w1;
            cc[2 * j] = (int)p[0];     w0.u = p[1];
            cc[2 * j + 1] = (int)p[2]; w1.u = p[3];
            vv[2 * j] = w0.f; vv[2 * j + 1] = w1.f;
        }
        if (act) {
            u32x4 g[8];
#pragma unroll
            for (int j = 0; j < 8; ++j) {
                u32 c = (u32)cc[j]; if (c >= NN) c = 0;
                g[j] = *(const u32x4*)(xl + (size_t)c * 320);
            }
#pragma unroll
            for (int j = 0; j < 8; ++j) {
                float v = vv[j];
#pragma unroll
                for (int q = 0; q < 4; ++q) {
                    union { u32 i; float f; } lo, hi;
                    lo.i = g[j][q] << 16; hi.i = g[j][q] & 0xffff0000u;
                    a[2 * q] = fmaf(v, lo.f, a[2 * q]);
                    a[2 * q + 1] = fmaf(v, hi.f, a[2 * q + 1]);
                }
            }
        }
    }
    if (bias1 && lane < 25) {
#pragma unroll
        for (int q = 0; q < 8; ++q) a[q] += bias1[lane * 8 + q];
    }
    u32x4 o;
    o[0] = pack2(a[0], a[1]); o[1] = pack2(a[2], a[3]);
    o[2] = pack2(a[4], a[5]); o[3] = pack2(a[6], a[7]);
    if (lane < 25) {
        *(u32x4*)((u32*)Y1 + (size_t)r * 320 + lane * 4) = o;
    } else if (lane < 50) {
        *(u32x4*)((u32*)Yt + (size_t)r * 100 + (lane - 25) * 4) = o;
    }
}

// ---------------- width-200 spmm: one wave per row, 8 gathers in flight --------------
__global__ __launch_bounds__(256) void spmm200_k(
    const int* __restrict__ row_ptr, const int* __restrict__ edges,
    const u16* __restrict__ X, int ldx,
    u16* __restrict__ Y, int ldy,
    const float* __restrict__ bias) {
    int r = blockIdx.x * 4 + (threadIdx.x >> 6);
    if (r >= NN) return;
    int lane = threadIdx.x & 63;
    int s = row_ptr[r], e = row_ptr[r + 1];
    if (s < 0) s = 0;
    if (e < s) e = s;
    float a[4] = {0.f, 0.f, 0.f, 0.f};
    const bool act = lane < 50;
    const int ldxw = ldx >> 1, ldyw = ldy >> 1;
    const u32* xl = (const u32*)X + lane * 2;
    for (int i = s; i < e; i += 8) {
        int cc[8]; float vv[8];
#pragma unroll
        for (int j = 0; j < 4; ++j) {
            u32x4 p = *(const u32x4*)(edges + 2 * (size_t)(i + 2 * j));
            union { u32 u; float f; } w0, w1;
            cc[2 * j] = (int)p[0];     w0.u = p[1];
            cc[2 * j + 1] = (int)p[2]; w1.u = p[3];
            vv[2 * j] = w0.f; vv[2 * j + 1] = w1.f;
        }
        if (act) {
            u32x2 g[8];
#pragma unroll
            for (int j = 0; j < 8; ++j) {
                u32 c = (u32)cc[j]; if (c >= NN) c = 0;
                g[j] = *(const u32x2*)(xl + (size_t)c * ldxw);
            }
#pragma unroll
            for (int j = 0; j < 8; ++j) {
                float v = vv[j];
#pragma unroll
                for (int q = 0; q < 2; ++q) {
                    union { u32 i; float f; } lo, hi;
                    lo.i = g[j][q] << 16; hi.i = g[j][q] & 0xffff0000u;
                    a[2 * q] = fmaf(v, lo.f, a[2 * q]);
                    a[2 * q + 1] = fmaf(v, hi.f, a[2 * q + 1]);
                }
            }
        }
    }
    if (bias && act) {
#pragma unroll
        for (int q = 0; q < 4; ++q) a[q] += bias[lane * 4 + q];
    }
    if (act) {
        u32x2 o;
        o[0] = pack2(a[0], a[1]); o[1] = pack2(a[2], a[3]);
        *(u32x2*)((u32*)Y + (size_t)r * ldyw + lane * 2) = o;
    }
}

extern "C" void kernel_launch(void* const* d_in, const int* in_sizes, int n_in,
                              void* d_out, int out_size, void* d_ws, size_t ws_size,
                              hipStream_t stream) {
    const int* adj_idx = (const int*)d_in[0];
    const void* adj_vals = d_in[1];
    const void* feats = d_in[2];
    const void* W1 = d_in[3];
    const void* b1 = d_in[4];
    const void* W2 = d_in[5];
    const void* b2 = d_in[6];
    const void* Wfc = d_in[7];
    const void* bfc = d_in[8];
    const int E = in_sizes[1];
    (void)n_in; (void)out_size; (void)ws_size;

    char* ws = (char*)d_ws;
    size_t off = 0;
    auto alloc = [&](size_t b) { size_t o = off; off += (b + 255) & ~(size_t)255; return o; };
    u16* buf0 = (u16*)(ws + alloc((size_t)NN * PAD * 2));   // U, then V
    u16* buf1 = (u16*)(ws + alloc((size_t)NN * PAD * 2));   // abstract1, stage-2 hops
    u16* hop = (u16*)(ws + alloc((size_t)NN * 200 * 2));
    u16* w1t = (u16*)(ws + alloc((size_t)640 * 512 * 2));
    u16* w2t = (u16*)(ws + alloc((size_t)640 * 640 * 2));
    u16* wfct = (u16*)(ws + alloc((size_t)64 * 640 * 2));
    float* biasf = (float*)(ws + alloc(1344 * 4));  // b1|b2|bfc|bfc_adj(1280+)
    int* counts = (int*)(ws + alloc((size_t)NN * 4));
    int* cursor = (int*)(ws + alloc((size_t)NN * 4));
    int* row_ptr = (int*)(ws + alloc((size_t)(NN + 1) * 4));
    int* chsum = (int*)(ws + alloc(4096));
    int* choff = (int*)(ws + alloc(4096));
    int* flags = (int*)(ws + alloc(256));
    // interleaved (col, val) pairs; padded to multiple of 8 per row
    int* edgesS = (int*)(ws + alloc(((size_t)E + 8 * (size_t)NN) * 8));

    float* out_ne = (float*)d_out;              // fp32 node_emb
    float* out_pred = out_ne + (size_t)NN * 64; // fp32 log-softmax

    // probes + weight prep
    probe_k<<<1, 64, 0, stream>>>(adj_idx, adj_vals, feats, W1, b1, W2, b2, Wfc, bfc, flags);
    dim3 gp(1600, 5);
    prep_k<<<gp, 256, 0, stream>>>(W1, W2, Wfc, b1, b2, bfc, w1t, w2t, wfct, biasf, flags);

    // CSR build (padded to 8 edges/row)
    hipMemsetAsync(counts, 0, NN * 4, stream);
    count_k<<<(E + 255) / 256, 256, 0, stream>>>(adj_idx, E, flags, counts);
    const int NCH = (NN + 1023) / 1024;  // 98
    chunksum_k<<<NCH, 256, 0, stream>>>(counts, chsum);
    chscan_k<<<1, 64, 0, stream>>>(chsum, NCH, choff, row_ptr, E);
    scan_k<<<NCH, 1024, 0, stream>>>(counts, choff, row_ptr, cursor);
    scatter_k<<<(E + 255) / 256, 256, 0, stream>>>(adj_idx, adj_vals, E, flags, cursor, edgesS);
    padfill_k<<<(NN + 255) / 256, 256, 0, stream>>>(cursor, row_ptr, edgesS);

    const int NWG = ((NN + 255) / 256) * 5;  // 391 M-tiles x 5 N-tiles = 1955
    // U = relu(feats @ W1all + b1) -> buf0; side-copy block0 + zero pad -> buf1
    gemm1_k<<<NWG, 512, 0, stream>>>(feats, w1t, buf0, buf1, biasf, flags, NN, 512, 512, PAD);
    // abstract1 -> buf1: hop1 (width 400 fused) + hop2
    spmm400_k<<<(NN + 3) / 4, 256, 0, stream>>>(row_ptr, edgesS,
                                                buf0 + 200, buf1 + 200, hop, nullptr);
    spmm200_k<<<(NN + 3) / 4, 256, 0, stream>>>(row_ptr, edgesS,
                                                hop, 200, buf1 + 400, PAD, nullptr);
    // V = abstract1 @ W2all -> buf0
    gemm2_k<<<NWG, 512, 0, stream>>>(buf1, w2t, buf0, NN, PAD, PAD, PAD);
    // stage-2 hops: read V (buf0 cols [200,600)); write buf1 cols [200,600)
    spmm400_k<<<(NN + 3) / 4, 256, 0, stream>>>(row_ptr, edgesS,
                                                buf0 + 200, buf1 + 200, hop, biasf + 800);
    spmm200_k<<<(NN + 3) / 4, 256, 0, stream>>>(row_ptr, edgesS,
                                                hop, 200, buf1 + 400, PAD, biasf + 1000);
    // node_emb + log_softmax fused -> d_out; gappy A: k<200 from buf0 (V0)
    fc64_k<<<(NN + 127) / 128, 256, 0, stream>>>(buf0, buf1, wfct, out_ne, out_pred,
                                                 biasf + 1280, NN, PAD, PAD);
}